// Round 13
// baseline (1350.426 us; speedup 1.0000x reference)
//
#include <hip/hip_runtime.h>
#include <stdint.h>

#define N_ROWS 262144
#define D_DIM  1024
#define H_DIM  512
#define N_SEG  512

typedef __attribute__((ext_vector_type(4)))  float  f32x4;
typedef __attribute__((ext_vector_type(8)))  __bf16 bf16x8;
typedef __attribute__((ext_vector_type(8)))  unsigned short u16x8;

static __device__ __forceinline__ unsigned short c2bf(float f) {
  union { __bf16 b; unsigned short u; } c; c.b = (__bf16)f; return c.u;   // RNE, pairs fuse to cvt_pk
}
static __device__ __forceinline__ float fast_tanh(float u) {
  return 1.0f - 2.0f / (__expf(2.0f * u) + 1.0f);
}

// ---------------- kernel 0: W1,W2 f32 -> bf16 LDS-image, u/v interleaved ----
// Image for (hs, kt): 16 KB = 16 subtiles (cfi) of 1 KB; subtile = lane l slot
// of 16 B: col c = cfi*16 + (l&15); mat = c&1 (0=W1,1=W2), h = hs*128 + (c>>1);
// k = kt*32 + (l>>4)*8 + e.  elem idx = (hs*32+kt)*8192 + cfi*512 + l*8 + e.
__global__ void cvt_w(const float* __restrict__ W1, const float* __restrict__ W2,
                      unsigned short* __restrict__ wbf) {
  int gid = blockIdx.x * 256 + threadIdx.x;      // 131072
  int l   = gid & 63;
  int cfi = (gid >> 6) & 15;
  int kt  = (gid >> 10) & 31;
  int hs  = gid >> 15;
  int c   = (cfi << 4) + (l & 15);
  int h   = (hs << 7) + (c >> 1);
  int k0  = (kt << 5) + ((l >> 4) << 3);
  const float* src = ((c & 1) ? W2 : W1) + h * 1024 + k0;
  f32x4 f0 = *(const f32x4*)src;
  f32x4 f1 = *(const f32x4*)(src + 4);
  u16x8 v;
  v[0]=c2bf(f0[0]); v[1]=c2bf(f0[1]); v[2]=c2bf(f0[2]); v[3]=c2bf(f0[3]);
  v[4]=c2bf(f1[0]); v[5]=c2bf(f1[1]); v[6]=c2bf(f1[2]); v[7]=c2bf(f1[3]);
  *(u16x8*)(wbf + (size_t)gid * 8) = v;
}

// ---------------- kernel 1: partial (m,s,n) per (row, h-slice) -------------
// 256-sq port of the m201 structure: block = 256 rows x 256 vcols, 512 thr,
// 8 waves = 2rg x 4cg, wave = 128r x 64c, acc f32x4[8][4] (128 AGPR, 2 w/SIMD).
// Per kt (BK=32): 4 sub-phases, one C-quadrant (8 MFMA) each, reads/stages
// interleaved per-quadrant; counted vmcnt(4) at kt end (A-loads in flight).
// A: f32->reg (kt+2 ahead) -> pack-late to LDS (kt+1). B: gload_lds image.
#define MF(A, B, C) __builtin_amdgcn_mfma_f32_16x16x32_bf16((A), (B), (C), 0, 0, 0)

#define STAGEB(KT, BOFF) do { \
  __builtin_amdgcn_global_load_lds( \
    (const __attribute__((address_space(1))) void*)(wsrc + ((uint32_t)(KT) << 13)), \
    (__attribute__((address_space(3))) void*)(lds + (BOFF) + (wid << 11)), 16, 0, 0); \
  __builtin_amdgcn_global_load_lds( \
    (const __attribute__((address_space(1))) void*)(wsrc + ((uint32_t)(KT) << 13) + 512), \
    (__attribute__((address_space(3))) void*)(lds + (BOFF) + (wid << 11) + 1024), 16, 0, 0); \
} while (0)

#define ALOAD(KT) do { \
  rA0 = *(const f32x4*)(xsrc0 + ((KT) << 5)); rA1 = *(const f32x4*)(xsrc0 + ((KT) << 5) + 4); \
  rB0 = *(const f32x4*)(xsrc1 + ((KT) << 5)); rB1 = *(const f32x4*)(xsrc1 + ((KT) << 5) + 4); \
} while (0)

#define PACKA(BOFF) do { \
  u16x8 va, vb; \
  va[0]=c2bf(rA0[0]); va[1]=c2bf(rA0[1]); va[2]=c2bf(rA0[2]); va[3]=c2bf(rA0[3]); \
  va[4]=c2bf(rA1[0]); va[5]=c2bf(rA1[1]); va[6]=c2bf(rA1[2]); va[7]=c2bf(rA1[3]); \
  vb[0]=c2bf(rB0[0]); vb[1]=c2bf(rB0[1]); vb[2]=c2bf(rB0[2]); vb[3]=c2bf(rB0[3]); \
  vb[4]=c2bf(rB1[0]); vb[5]=c2bf(rB1[1]); vb[6]=c2bf(rB1[2]); vb[7]=c2bf(rB1[3]); \
  *(u16x8*)(lds + (BOFF) + (tid << 4)) = va; \
  *(u16x8*)(lds + (BOFF) + 8192 + (tid << 4)) = vb; \
} while (0)

#define LDB(BUF, FC) (*(const bf16x8*)(lds + (BUF) + (((cg << 2) + (FC)) << 10) + (lane << 4)))
#define LDA(BUF, FR) (*(const bf16x8*)(lds + (BUF) + (((rg << 3) + (FR)) << 10) + (lane << 4)))

#define MFQ(I0, A0_, A1_, A2_, A3_, B0_, B1_) do { \
  __builtin_amdgcn_s_setprio(1); \
  acc[I0+0][0] = MF(A0_, B0_, acc[I0+0][0]); acc[I0+0][1] = MF(A0_, B1_, acc[I0+0][1]); \
  acc[I0+1][0] = MF(A1_, B0_, acc[I0+1][0]); acc[I0+1][1] = MF(A1_, B1_, acc[I0+1][1]); \
  acc[I0+2][0] = MF(A2_, B0_, acc[I0+2][0]); acc[I0+2][1] = MF(A2_, B1_, acc[I0+2][1]); \
  acc[I0+3][0] = MF(A3_, B0_, acc[I0+3][0]); acc[I0+3][1] = MF(A3_, B1_, acc[I0+3][1]); \
  __builtin_amdgcn_s_setprio(0); \
} while (0)
#define MFQ2(I0, A0_, A1_, A2_, A3_, B2_, B3_) do { \
  __builtin_amdgcn_s_setprio(1); \
  acc[I0+0][2] = MF(A0_, B2_, acc[I0+0][2]); acc[I0+0][3] = MF(A0_, B3_, acc[I0+0][3]); \
  acc[I0+1][2] = MF(A1_, B2_, acc[I0+1][2]); acc[I0+1][3] = MF(A1_, B3_, acc[I0+1][3]); \
  acc[I0+2][2] = MF(A2_, B2_, acc[I0+2][2]); acc[I0+2][3] = MF(A2_, B3_, acc[I0+2][3]); \
  acc[I0+3][2] = MF(A3_, B2_, acc[I0+3][2]); acc[I0+3][3] = MF(A3_, B3_, acc[I0+3][3]); \
  __builtin_amdgcn_s_setprio(0); \
} while (0)

// One kt: 4 sub-phases (quadrants). AB/BB = read bufs; AO/BO = stage bufs.
// Stages B(KT+1)->BO, packs A(KT+1)->AO (regs from last kt), loads A(KT+2).
#define PHASE(AB, BB, AO, BO, KT, DOALOAD) do { \
  /* SP0: quadrant fr0-3 x fc0-1 */ \
  bf16x8 a0 = LDA(AB, 0), a1 = LDA(AB, 1), a2 = LDA(AB, 2), a3 = LDA(AB, 3); \
  bf16x8 b0 = LDB(BB, 0), b1 = LDB(BB, 1); \
  STAGEB((KT) + 1, BO); \
  __builtin_amdgcn_s_barrier(); \
  asm volatile("s_waitcnt lgkmcnt(0)" ::: "memory"); \
  MFQ(0, a0, a1, a2, a3, b0, b1); \
  __builtin_amdgcn_s_barrier(); \
  /* SP1: quadrant fr0-3 x fc2-3 */ \
  bf16x8 b2 = LDB(BB, 2), b3 = LDB(BB, 3); \
  PACKA(AO); \
  __builtin_amdgcn_s_barrier(); \
  asm volatile("s_waitcnt lgkmcnt(0)" ::: "memory"); \
  MFQ2(0, a0, a1, a2, a3, b2, b3); \
  __builtin_amdgcn_s_barrier(); \
  /* SP2: quadrant fr4-7 x fc0-1 */ \
  bf16x8 a4 = LDA(AB, 4), a5 = LDA(AB, 5), a6 = LDA(AB, 6), a7 = LDA(AB, 7); \
  if (DOALOAD) ALOAD((KT) + 2); \
  __builtin_amdgcn_s_barrier(); \
  asm volatile("s_waitcnt lgkmcnt(0)" ::: "memory"); \
  MFQ(4, a4, a5, a6, a7, b0, b1); \
  __builtin_amdgcn_s_barrier(); \
  /* SP3: quadrant fr4-7 x fc2-3 */ \
  MFQ2(4, a4, a5, a6, a7, b2, b3); \
  asm volatile("s_waitcnt vmcnt(4)" ::: "memory"); \
  __builtin_amdgcn_s_barrier(); \
} while (0)

__launch_bounds__(512, 2)
__global__ void alpha_kernel(const float* __restrict__ x,
                             const unsigned short* __restrict__ wbf,
                             const float* __restrict__ W3,
                             float* __restrict__ pm, float* __restrict__ ps,
                             float* __restrict__ pn)
{
  __shared__ unsigned char lds[65536];           // A0@0 A1@16K B0@32K B1@48K
  const int tid  = threadIdx.x;
  const int lane = tid & 63;
  const int wid  = tid >> 6;                     // 0..7
  const int rg   = wid >> 2;                     // 0..1  row half (128 rows)
  const int cg   = wid & 3;                      // 0..3  col quarter (64 vcols)
  const int l15  = lane & 15;
  const int lg   = lane >> 4;                    // 0..3
  const int bid  = blockIdx.x;
  const int rt   = ((bid >> 5) << 3) + (bid & 7);   // rowtile 0..1023 (hs same XCD)
  const int hs   = (bid >> 3) & 3;                  // h-slice 0..3
  const int row0 = rt << 8;                         // 256 rows/block

  // A staging (R9-verified): thread t -> slots t, t+512; slot s:
  // row = (s>>6)*16 + (s&15), k = kt*32 + ((s>>4)&3)*8 + [0,8)
  const int s0r = ((tid >> 6) << 4) + (tid & 15);
  const int s0k = ((tid >> 4) & 3) << 3;
  const float* xsrc0 = x + (size_t)(row0 + s0r) * 1024 + s0k;
  const float* xsrc1 = xsrc0 + (size_t)128 * 1024;

  // B staging source (per-lane), image from cvt_w
  const unsigned short* wsrc = wbf + ((uint32_t)hs << 18) + ((uint32_t)wid << 10) + ((uint32_t)lane << 3);

  f32x4 acc[8][4];
  #pragma unroll
  for (int fr = 0; fr < 8; ++fr)
    #pragma unroll
    for (int fc = 0; fc < 4; ++fc) acc[fr][fc] = (f32x4){0.f, 0.f, 0.f, 0.f};

  f32x4 rA0, rA1, rB0, rB1;

  // ---- prologue ----
  STAGEB(0, 32768);                              // B(0) -> B0
  ALOAD(0);
  PACKA(0);                                      // A(0) -> A0 (auto-waits own loads)
  ALOAD(1);                                      // for pack at kt0 SP1 -> A1
  asm volatile("s_waitcnt vmcnt(4) lgkmcnt(0)" ::: "memory");  // B(0)+A(0) drained
  __builtin_amdgcn_s_barrier();

  // ---- kt = 0..29 in pairs ----
  #pragma unroll 1
  for (int kt = 0; kt < 30; kt += 2) {
    PHASE(0,     32768, 16384, 49152, kt,     1);   // A0xB0; ->A1,B1
    PHASE(16384, 49152, 0,     32768, kt + 1, 1);   // A1xB1; ->A0,B0
  }
  // kt = 30: A0 x B0; stage B(31)->B1; pack A(31)->A1; no ALOAD
  PHASE(0, 32768, 16384, 49152, 30, 0);
  // kt = 31: drain, then compute A1 x B1 in one cluster
  asm volatile("s_waitcnt vmcnt(0) lgkmcnt(0)" ::: "memory");
  __builtin_amdgcn_s_barrier();
  {
    bf16x8 a0 = LDA(16384, 0), a1 = LDA(16384, 1), a2 = LDA(16384, 2), a3 = LDA(16384, 3);
    bf16x8 a4 = LDA(16384, 4), a5 = LDA(16384, 5), a6 = LDA(16384, 6), a7 = LDA(16384, 7);
    bf16x8 b0 = LDB(49152, 0), b1 = LDB(49152, 1), b2 = LDB(49152, 2), b3 = LDB(49152, 3);
    MFQ(0, a0, a1, a2, a3, b0, b1);
    MFQ2(0, a0, a1, a2, a3, b2, b3);
    MFQ(4, a4, a5, a6, a7, b0, b1);
    MFQ2(4, a4, a5, a6, a7, b2, b3);
  }
  __builtin_amdgcn_s_barrier();

  // ---- epilogue (R11-verified, static, in-register via shfl) ----
  // C/D map (m89): col = lane&15, row = lg*4 + j. Lane's col c = cg*64+fc*16+l15;
  // parity(c) = parity(lane): even lane = u[h], odd lane = v-logit[h],
  // h = hs*128 + (c>>1); shfl_xor(1) moves the gate across.
  float w3v[4];
  #pragma unroll
  for (int fc = 0; fc < 4; ++fc)
    w3v[fc] = W3[(hs << 7) + (((cg << 6) + (fc << 4) + l15) >> 1)];

  float* pmb = (float*)(lds);                    // [4 cg][256 rows], aliases A0
  float* psb = pmb + 1024;
  float* pnb = psb + 1024;

  #pragma unroll
  for (int fr = 0; fr < 8; ++fr) {
    f32x4 mv, sv, nv;
    #pragma unroll
    for (int j = 0; j < 4; ++j) {
      float g0 = fast_tanh(acc[fr][0][j]) * w3v[0];
      float g1 = fast_tanh(acc[fr][1][j]) * w3v[1];
      float g2 = fast_tanh(acc[fr][2][j]) * w3v[2];
      float g3 = fast_tanh(acc[fr][3][j]) * w3v[3];
      float gs0 = __shfl_xor(g0, 1);
      float gs1 = __shfl_xor(g1, 1);
      float gs2 = __shfl_xor(g2, 1);
      float gs3 = __shfl_xor(g3, 1);
      float mj = fmaxf(fmaxf(acc[fr][0][j], acc[fr][1][j]),
                       fmaxf(acc[fr][2][j], acc[fr][3][j]));
      mj = fmaxf(mj, __shfl_xor(mj, 2));
      mj = fmaxf(mj, __shfl_xor(mj, 4));
      mj = fmaxf(mj, __shfl_xor(mj, 8));
      float p0 = __expf(acc[fr][0][j] - mj);
      float p1 = __expf(acc[fr][1][j] - mj);
      float p2 = __expf(acc[fr][2][j] - mj);
      float p3 = __expf(acc[fr][3][j] - mj);
      float sj = p0 + p1 + p2 + p3;
      float nj = gs0 * p0 + gs1 * p1 + gs2 * p2 + gs3 * p3;
      sj += __shfl_xor(sj, 2); nj += __shfl_xor(nj, 2);
      sj += __shfl_xor(sj, 4); nj += __shfl_xor(nj, 4);
      sj += __shfl_xor(sj, 8); nj += __shfl_xor(nj, 8);
      mv[j] = mj; sv[j] = sj; nv[j] = nj;
    }
    if (l15 == 1) {                              // lanes 1,17,33,49 (one per lg)
      int idx = (cg << 8) + (rg << 7) + (fr << 4) + (lg << 2);
      *(f32x4*)&pmb[idx] = mv;
      *(f32x4*)&psb[idx] = sv;
      *(f32x4*)&pnb[idx] = nv;
    }
  }
  __syncthreads();
  if (tid < 256) {
    float m0 = pmb[tid], m1 = pmb[256 + tid], m2 = pmb[512 + tid], m3 = pmb[768 + tid];
    float M = fmaxf(fmaxf(m0, m1), fmaxf(m2, m3));
    float e0 = __expf(m0 - M), e1 = __expf(m1 - M), e2 = __expf(m2 - M), e3 = __expf(m3 - M);
    float S  = psb[tid]*e0 + psb[256+tid]*e1 + psb[512+tid]*e2 + psb[768+tid]*e3;
    float Nn = pnb[tid]*e0 + pnb[256+tid]*e1 + pnb[512+tid]*e2 + pnb[768+tid]*e3;
    size_t r = (size_t)(row0 + tid);
    pm[r * 4 + hs] = M;
    ps[r * 4 + hs] = S;
    pn[r * 4 + hs] = Nn;
  }
}

// ---------------- kernel 1b: combine h-slice partials -> a[i] --------------
__global__ void combine_a(const float* __restrict__ pm, const float* __restrict__ ps,
                          const float* __restrict__ pn, float* __restrict__ a) {
  size_t r = (size_t)blockIdx.x * 256 + threadIdx.x;
  float M = -3.4e38f;
  #pragma unroll
  for (int s = 0; s < 4; ++s) M = fmaxf(M, pm[r * 4 + s]);
  float S = 0.f, Nn = 0.f;
  #pragma unroll
  for (int s = 0; s < 4; ++s) {
    float e = __expf(pm[r * 4 + s] - M);
    S  += ps[r * 4 + s] * e;
    Nn += pn[r * 4 + s] * e;
  }
  a[r] = Nn / S;
}

// ---------------- kernel 2: segment softmax weights ----------------
static __device__ __forceinline__ int lower_bound(const int* __restrict__ batch, int key) {
  int lo = 0, hi = N_ROWS;
  while (lo < hi) { int mid = (lo + hi) >> 1; if (batch[mid] < key) lo = mid + 1; else hi = mid; }
  return lo;
}

__global__ void seg_kernel(const float* __restrict__ a, const int* __restrict__ batch,
                           float* __restrict__ w) {
  __shared__ float sm[8];
  int b = blockIdx.x;
  int start = lower_bound(batch, b);
  int end   = lower_bound(batch, b + 1);
  int tid = threadIdx.x;

  float m = -3.4e38f;
  for (int i = start + tid; i < end; i += 256) m = fmaxf(m, a[i]);
  for (int d = 1; d < 64; d <<= 1) m = fmaxf(m, __shfl_xor(m, d));
  if ((tid & 63) == 0) sm[tid >> 6] = m;
  __syncthreads();
  m = fmaxf(fmaxf(sm[0], sm[1]), fmaxf(sm[2], sm[3]));

  float s = 0.f;
  for (int i = start + tid; i < end; i += 256) s += __expf(a[i] - m);
  for (int d = 1; d < 64; d <<= 1) s += __shfl_xor(s, d);
  if ((tid & 63) == 0) sm[4 + (tid >> 6)] = s;
  __syncthreads();
  s = sm[4] + sm[5] + sm[6] + sm[7];

  float rinv = 1.0f / s;
  for (int i = start + tid; i < end; i += 256) w[i] = __expf(a[i] - m) * rinv;
}

// ---------------- kernel 3: z[b] = sum_i w_i * x_i ----------------
__global__ void z_kernel(const float* __restrict__ x, const float* __restrict__ w,
                         const int* __restrict__ batch, float* __restrict__ z) {
  int b = blockIdx.x >> 2, part = blockIdx.x & 3;
  int start = lower_bound(batch, b);
  int end   = lower_bound(batch, b + 1);
  int len = end - start;
  int ps = start + ((len * part) >> 2);
  int pe = start + ((len * (part + 1)) >> 2);
  int col = threadIdx.x << 2;

  f32x4 acc = (f32x4){0.f, 0.f, 0.f, 0.f};
  for (int i = ps; i < pe; ++i) {
    f32x4 xv = *(const f32x4*)(x + ((size_t)i << 10) + col);
    float wi = w[i];
    acc += xv * wi;
  }
  float* zp = z + ((size_t)b << 10) + col;
  atomicAdd(zp + 0, acc[0]);
  atomicAdd(zp + 1, acc[1]);
  atomicAdd(zp + 2, acc[2]);
  atomicAdd(zp + 3, acc[3]);
}

// ---------------- launch ----------------
extern "C" void kernel_launch(void* const* d_in, const int* in_sizes, int n_in,
                              void* d_out, int out_size, void* d_ws, size_t ws_size,
                              hipStream_t stream) {
  const float* x     = (const float*)d_in[0];
  const int*   batch = (const int*)d_in[1];
  const float* W1    = (const float*)d_in[2];
  const float* W2    = (const float*)d_in[3];
  const float* W3    = (const float*)d_in[4];
  float* z = (float*)d_out;

  // ws: [0,2M) wbf ; [2M,3M) a ; [3M,4M) w ; [4M,8M) pm ; [8M,12M) ps ; [12M,16M) pn
  unsigned short* wbf = (unsigned short*)d_ws;
  float* a  = (float*)((char*)d_ws + (2u << 20));
  float* w  = (float*)((char*)d_ws + (3u << 20));
  float* pm = (float*)((char*)d_ws + (4u << 20));
  float* ps = (float*)((char*)d_ws + (8u << 20));
  float* pn = (float*)((char*)d_ws + (12u << 20));

  (void)hipMemsetAsync(d_out, 0, (size_t)N_SEG * D_DIM * sizeof(float), stream);

  cvt_w<<<512, 256, 0, stream>>>(W1, W2, wbf);

  alpha_kernel<<<4096, 512, 0, stream>>>(x, wbf, W3, pm, ps, pn);

  combine_a<<<N_ROWS / 256, 256, 0, stream>>>(pm, ps, pn, a);

  seg_kernel<<<N_SEG, 256, 0, stream>>>(a, batch, w);

  z_kernel<<<N_SEG * 4, 256, 0, stream>>>(x, w, batch, z);
}

// Round 14
// 1237.398 us; speedup vs baseline: 1.0913x; 1.0913x over previous
//
#include <hip/hip_runtime.h>
#include <stdint.h>

#define N_ROWS 262144
#define D_DIM  1024
#define H_DIM  512
#define N_SEG  512

typedef __attribute__((ext_vector_type(4)))  float  f32x4;
typedef __attribute__((ext_vector_type(8)))  __bf16 bf16x8;
typedef __attribute__((ext_vector_type(8)))  unsigned short u16x8;

static __device__ __forceinline__ unsigned short c2bf(float f) {
  union { __bf16 b; unsigned short u; } c; c.b = (__bf16)f; return c.u;
}
static __device__ __forceinline__ float fast_tanh(float u) {
  return 1.0f - 2.0f / (__expf(2.0f * u) + 1.0f);
}

// ---------------- kernel 0: W1,W2 f32 -> bf16 LDS-image, u/v interleaved ----
// Image for (hs, kt): 16 KB = 16 frags (cfi) of 1 KB; frag slot l (16B):
// col c = cfi*16 + (l&15); mat = c&1 (0=W1,1=W2), h = hs*128 + (c>>1);
// k = kt*32 + (l>>4)*8 + e.  elem idx = (hs*32+kt)*8192 + cfi*512 + l*8 + e.
__global__ void cvt_w(const float* __restrict__ W1, const float* __restrict__ W2,
                      unsigned short* __restrict__ wbf) {
  int gid = blockIdx.x * 256 + threadIdx.x;      // 131072
  int l   = gid & 63;
  int cfi = (gid >> 6) & 15;
  int kt  = (gid >> 10) & 31;
  int hs  = gid >> 15;
  int c   = (cfi << 4) + (l & 15);
  int h   = (hs << 7) + (c >> 1);
  int k0  = (kt << 5) + ((l >> 4) << 3);
  const float* src = ((c & 1) ? W2 : W1) + h * 1024 + k0;
  f32x4 f0 = *(const f32x4*)src;
  f32x4 f1 = *(const f32x4*)(src + 4);
  u16x8 v;
  v[0]=c2bf(f0[0]); v[1]=c2bf(f0[1]); v[2]=c2bf(f0[2]); v[3]=c2bf(f0[3]);
  v[4]=c2bf(f1[0]); v[5]=c2bf(f1[1]); v[6]=c2bf(f1[2]); v[7]=c2bf(f1[3]);
  *(u16x8*)(wbf + (size_t)gid * 8) = v;
}

// ---------------- kernel 0b: x f32 -> bf16 A-image (per 64-rowtile chunk) ----
// A K-tile (256r x 32k) = 1024 slots x 16B. Slot s = f*64 + r4*4 + c:
// holds x[rt*256 + f*16 + r4, kt*32 + (c^(r4&3))*8 .. +8)  (XOR de-conflicts
// the stride-64B frag read to 2-way = free). elem idx (per chunk, rtl local):
// (rtl<<15 + kt<<10 + s)*8 == gid*8.
__global__ void cvt_x(const float* __restrict__ x, unsigned short* __restrict__ ximg,
                      int chunk) {
  int gid = blockIdx.x * 256 + threadIdx.x;      // [0, 2^21)
  int s   = gid & 1023;
  int kt  = (gid >> 10) & 31;
  int rtl = gid >> 15;                           // [0,64)
  int f   = s >> 6;
  int j   = s & 63;
  int r4  = j >> 2;
  int c   = j & 3;
  int row = (((chunk << 6) + rtl) << 8) + (f << 4) + r4;
  int k0  = (kt << 5) + ((c ^ (r4 & 3)) << 3);
  const float* src = x + (size_t)row * 1024 + k0;
  f32x4 f0 = *(const f32x4*)src;
  f32x4 f1 = *(const f32x4*)(src + 4);
  u16x8 v;
  v[0]=c2bf(f0[0]); v[1]=c2bf(f0[1]); v[2]=c2bf(f0[2]); v[3]=c2bf(f0[3]);
  v[4]=c2bf(f1[0]); v[5]=c2bf(f1[1]); v[6]=c2bf(f1[2]); v[7]=c2bf(f1[3]);
  *(u16x8*)(ximg + (size_t)gid * 8) = v;
}

// ---------------- shared GEMM building blocks ----------------
#define MF(A, B, C) __builtin_amdgcn_mfma_f32_16x16x32_bf16((A), (B), (C), 0, 0, 0)

#define STAGEB(KT, BOFF) do { \
  __builtin_amdgcn_global_load_lds( \
    (const __attribute__((address_space(1))) void*)(wsrc + ((uint32_t)(KT) << 13)), \
    (__attribute__((address_space(3))) void*)(lds + (BOFF) + (wid << 11)), 16, 0, 0); \
  __builtin_amdgcn_global_load_lds( \
    (const __attribute__((address_space(1))) void*)(wsrc + ((uint32_t)(KT) << 13) + 512), \
    (__attribute__((address_space(3))) void*)(lds + (BOFF) + (wid << 11) + 1024), 16, 0, 0); \
} while (0)

#define LDB(BUF, FC) (*(const bf16x8*)(lds + (BUF) + (((cg << 2) + (FC)) << 10) + (lane << 4)))

// ============ FAST PATH: m201-style pure-DMA 256x256 GEMM ============
#define FAST_A0 0
#define FAST_A1 16384
#define FAST_A2 32768
#define FAST_B0 49152
#define FAST_B1 65536
#define FAST_B2 81920

#define STAGEA(KT, AOFF) do { \
  __builtin_amdgcn_global_load_lds( \
    (const __attribute__((address_space(1))) void*)(asrc + ((uint32_t)(KT) << 13)), \
    (__attribute__((address_space(3))) void*)(lds + (AOFF) + (wid << 10)), 16, 0, 0); \
  __builtin_amdgcn_global_load_lds( \
    (const __attribute__((address_space(1))) void*)(asrc + ((uint32_t)(KT) << 13) + 4096), \
    (__attribute__((address_space(3))) void*)(lds + (AOFF) + (wid << 10) + 8192), 16, 0, 0); \
} while (0)

#define LDA8(BUF, FR) (*(const bf16x8*)(lds + (BUF) + (((rg << 3) + (FR)) << 10) + abase))

#define MFQ16(FB, A0_, A1_, A2_, A3_) do { \
  acc[(FB)+0][0]=MF(A0_,b0,acc[(FB)+0][0]); acc[(FB)+0][1]=MF(A0_,b1,acc[(FB)+0][1]); \
  acc[(FB)+0][2]=MF(A0_,b2,acc[(FB)+0][2]); acc[(FB)+0][3]=MF(A0_,b3,acc[(FB)+0][3]); \
  acc[(FB)+1][0]=MF(A1_,b0,acc[(FB)+1][0]); acc[(FB)+1][1]=MF(A1_,b1,acc[(FB)+1][1]); \
  acc[(FB)+1][2]=MF(A1_,b2,acc[(FB)+1][2]); acc[(FB)+1][3]=MF(A1_,b3,acc[(FB)+1][3]); \
  acc[(FB)+2][0]=MF(A2_,b0,acc[(FB)+2][0]); acc[(FB)+2][1]=MF(A2_,b1,acc[(FB)+2][1]); \
  acc[(FB)+2][2]=MF(A2_,b2,acc[(FB)+2][2]); acc[(FB)+2][3]=MF(A2_,b3,acc[(FB)+2][3]); \
  acc[(FB)+3][0]=MF(A3_,b0,acc[(FB)+3][0]); acc[(FB)+3][1]=MF(A3_,b1,acc[(FB)+3][1]); \
  acc[(FB)+3][2]=MF(A3_,b2,acc[(FB)+3][2]); acc[(FB)+3][3]=MF(A3_,b3,acc[(FB)+3][3]); \
} while (0)

// One K-tile: 2 MFMA clusters of 16, reads interleaved, counted vmcnt.
#define KTILE(RA, RB, SA, SB, KT, DOSTAGE, VMSTR) do { \
  bf16x8 b0 = LDB(RB,0), b1 = LDB(RB,1), b2 = LDB(RB,2), b3 = LDB(RB,3); \
  bf16x8 a0 = LDA8(RA,0), a1 = LDA8(RA,1), a2 = LDA8(RA,2), a3 = LDA8(RA,3); \
  if (DOSTAGE) { STAGEA((KT)+2, SA); STAGEB((KT)+2, SB); } \
  __builtin_amdgcn_s_barrier(); \
  asm volatile("s_waitcnt lgkmcnt(0)" ::: "memory"); \
  __builtin_amdgcn_s_setprio(1); MFQ16(0, a0, a1, a2, a3); __builtin_amdgcn_s_setprio(0); \
  __builtin_amdgcn_s_barrier(); \
  bf16x8 a4 = LDA8(RA,4), a5 = LDA8(RA,5), a6 = LDA8(RA,6), a7 = LDA8(RA,7); \
  __builtin_amdgcn_s_barrier(); \
  asm volatile("s_waitcnt lgkmcnt(0)" ::: "memory"); \
  __builtin_amdgcn_s_setprio(1); MFQ16(4, a4, a5, a6, a7); __builtin_amdgcn_s_setprio(0); \
  asm volatile("s_waitcnt vmcnt(" VMSTR ")" ::: "memory"); \
  __builtin_amdgcn_s_barrier(); \
} while (0)

__launch_bounds__(512, 2)
__global__ void alpha_fast(const unsigned short* __restrict__ ximg,
                           const unsigned short* __restrict__ wbf,
                           const float* __restrict__ W3,
                           float* __restrict__ pm, float* __restrict__ ps,
                           float* __restrict__ pn, int chunk)
{
  extern __shared__ unsigned char lds[];         // 98304: A x3 @0, B x3 @49152
  const int tid  = threadIdx.x;
  const int lane = tid & 63;
  const int wid  = tid >> 6;                     // 0..7
  const int rg   = wid >> 2;                     // 0..1  row half (128 rows)
  const int cg   = wid & 3;                      // 0..3  col quarter (64 vcols)
  const int l15  = lane & 15;
  const int lg   = lane >> 4;                    // 0..3
  const int bid  = blockIdx.x;                   // 256 blocks
  const int rtl  = ((bid >> 5) << 3) + (bid & 7);   // 0..63 (hs-group same XCD)
  const int hs   = (bid >> 3) & 3;
  const int rt   = (chunk << 6) + rtl;
  const int row0 = rt << 8;                      // 256 rows/block

  // staging sources
  const unsigned short* asrc = ximg + ((size_t)rtl << 18) + ((uint32_t)tid << 3);
  const unsigned short* wsrc = wbf + ((uint32_t)hs << 18) + ((uint32_t)wid << 10) + ((uint32_t)lane << 3);

  // A frag per-lane byte base (XOR layout; see cvt_x)
  const uint32_t abase = ((uint32_t)l15 << 6) + (((uint32_t)(lg ^ (l15 & 3))) << 4);

  f32x4 acc[8][4];
  #pragma unroll
  for (int fr = 0; fr < 8; ++fr)
    #pragma unroll
    for (int fc = 0; fc < 4; ++fc) acc[fr][fc] = (f32x4){0.f, 0.f, 0.f, 0.f};

  // prologue: stage K-tiles 0,1
  STAGEA(0, FAST_A0); STAGEB(0, FAST_B0);
  STAGEA(1, FAST_A1); STAGEB(1, FAST_B1);
  asm volatile("s_waitcnt vmcnt(4)" ::: "memory");   // tile 0 landed
  __builtin_amdgcn_s_barrier();

  #pragma unroll 1
  for (int kt = 0; kt < 30; kt += 3) {
    KTILE(FAST_A0, FAST_B0, FAST_A2, FAST_B2, kt,     1, "4");
    KTILE(FAST_A1, FAST_B1, FAST_A0, FAST_B0, kt + 1, 1, "4");
    KTILE(FAST_A2, FAST_B2, FAST_A1, FAST_B1, kt + 2, 1, "4");
  }
  KTILE(FAST_A0, FAST_B0, FAST_A2, FAST_B2, 30, 0, "0");  // drain tile-31 stages
  KTILE(FAST_A1, FAST_B1, FAST_A2, FAST_B2, 31, 0, "0");

  // ---- epilogue (R13-verified 256-row, static, in-register via shfl) ----
  // C/D map (m89): col = lane&15, row = lg*4 + j. Lane col c = cg*64+fc*16+l15;
  // parity(c)=parity(lane): even lane = u[h], odd = v-logit[h], h = hs*128+(c>>1).
  float w3v[4];
  #pragma unroll
  for (int fc = 0; fc < 4; ++fc)
    w3v[fc] = W3[(hs << 7) + (((cg << 6) + (fc << 4) + l15) >> 1)];

  float* pmb = (float*)(lds);                    // [4 cg][256 rows]
  float* psb = pmb + 1024;
  float* pnb = psb + 1024;

  #pragma unroll
  for (int fr = 0; fr < 8; ++fr) {
    f32x4 mv, sv, nv;
    #pragma unroll
    for (int j = 0; j < 4; ++j) {
      float g0 = fast_tanh(acc[fr][0][j]) * w3v[0];
      float g1 = fast_tanh(acc[fr][1][j]) * w3v[1];
      float g2 = fast_tanh(acc[fr][2][j]) * w3v[2];
      float g3 = fast_tanh(acc[fr][3][j]) * w3v[3];
      float gs0 = __shfl_xor(g0, 1);
      float gs1 = __shfl_xor(g1, 1);
      float gs2 = __shfl_xor(g2, 1);
      float gs3 = __shfl_xor(g3, 1);
      float mj = fmaxf(fmaxf(acc[fr][0][j], acc[fr][1][j]),
                       fmaxf(acc[fr][2][j], acc[fr][3][j]));
      mj = fmaxf(mj, __shfl_xor(mj, 2));
      mj = fmaxf(mj, __shfl_xor(mj, 4));
      mj = fmaxf(mj, __shfl_xor(mj, 8));
      float p0 = __expf(acc[fr][0][j] - mj);
      float p1 = __expf(acc[fr][1][j] - mj);
      float p2 = __expf(acc[fr][2][j] - mj);
      float p3 = __expf(acc[fr][3][j] - mj);
      float sj = p0 + p1 + p2 + p3;
      float nj = gs0 * p0 + gs1 * p1 + gs2 * p2 + gs3 * p3;
      sj += __shfl_xor(sj, 2); nj += __shfl_xor(nj, 2);
      sj += __shfl_xor(sj, 4); nj += __shfl_xor(nj, 4);
      sj += __shfl_xor(sj, 8); nj += __shfl_xor(nj, 8);
      mv[j] = mj; sv[j] = sj; nv[j] = nj;
    }
    if (l15 == 1) {
      int idx = (cg << 8) + (rg << 7) + (fr << 4) + (lg << 2);
      *(f32x4*)&pmb[idx] = mv;
      *(f32x4*)&psb[idx] = sv;
      *(f32x4*)&pnb[idx] = nv;
    }
  }
  __syncthreads();
  if (tid < 256) {
    float m0 = pmb[tid], m1 = pmb[256 + tid], m2 = pmb[512 + tid], m3 = pmb[768 + tid];
    float M = fmaxf(fmaxf(m0, m1), fmaxf(m2, m3));
    float e0 = __expf(m0 - M), e1 = __expf(m1 - M), e2 = __expf(m2 - M), e3 = __expf(m3 - M);
    float S  = psb[tid]*e0 + psb[256+tid]*e1 + psb[512+tid]*e2 + psb[768+tid]*e3;
    float Nn = pnb[tid]*e0 + pnb[256+tid]*e1 + pnb[512+tid]*e2 + pnb[768+tid]*e3;
    size_t r = (size_t)(row0 + tid);
    pm[r * 4 + hs] = M;
    ps[r * 4 + hs] = S;
    pn[r * 4 + hs] = Nn;
  }
}

// ============ FALLBACK (R11, known-good): reg-packed A, 128-row blocks ======
#define FB_ALOAD(KT) do { \
  rA0 = *(const f32x4*)(xsrc + ((KT) << 5)); \
  rA1 = *(const f32x4*)(xsrc + ((KT) << 5) + 4); \
} while (0)
#define FB_PACKA(BOFF) do { \
  u16x8 va; \
  va[0]=c2bf(rA0[0]); va[1]=c2bf(rA0[1]); va[2]=c2bf(rA0[2]); va[3]=c2bf(rA0[3]); \
  va[4]=c2bf(rA1[0]); va[5]=c2bf(rA1[1]); va[6]=c2bf(rA1[2]); va[7]=c2bf(rA1[3]); \
  *(u16x8*)(lds + (BOFF) + (tid << 4)) = va; \
} while (0)
#define FB_LDA(BUF, FR) (*(const bf16x8*)(lds + (BUF) + (((rg << 2) + (FR)) << 10) + (lane << 4)))
#define FB_COMPUTE(ABUF, BBUF) do { \
  bf16x8 bf_[4], af[4]; \
  _Pragma("unroll") \
  for (int fc = 0; fc < 4; ++fc) bf_[fc] = LDB(BBUF, fc); \
  _Pragma("unroll") \
  for (int fr = 0; fr < 4; ++fr) af[fr] = FB_LDA(ABUF, fr); \
  __builtin_amdgcn_s_setprio(1); \
  _Pragma("unroll") \
  for (int fr = 0; fr < 4; ++fr) \
    _Pragma("unroll") \
    for (int fc = 0; fc < 4; ++fc) \
      acc[fr][fc] = MF(af[fr], bf_[fc], acc[fr][fc]); \
  __builtin_amdgcn_s_setprio(0); \
} while (0)
#define FB_BAR2() do { \
  asm volatile("s_waitcnt vmcnt(2) lgkmcnt(0)" ::: "memory"); \
  __builtin_amdgcn_s_barrier(); \
} while (0)
#define FB_BAR0() do { \
  asm volatile("s_waitcnt vmcnt(0) lgkmcnt(0)" ::: "memory"); \
  __builtin_amdgcn_s_barrier(); \
} while (0)

__launch_bounds__(512, 4)
__global__ void alpha_fb(const float* __restrict__ x,
                         const unsigned short* __restrict__ wbf,
                         const float* __restrict__ W3,
                         float* __restrict__ pm, float* __restrict__ ps,
                         float* __restrict__ pn)
{
  __shared__ unsigned char lds[49152];
  const int tid  = threadIdx.x;
  const int lane = tid & 63;
  const int wid  = tid >> 6;
  const int rg   = wid >> 2;
  const int cg   = wid & 3;
  const int l15  = lane & 15;
  const int lg   = lane >> 4;
  const int bid  = blockIdx.x;
  const int rt   = ((bid >> 5) << 3) + (bid & 7);
  const int hs   = (bid >> 3) & 3;
  const int row0 = rt << 7;

  const float* xsrc = x + (size_t)(row0 + ((tid >> 6) << 4) + (tid & 15)) * 1024
                        + (((tid >> 4) & 3) << 3);
  const unsigned short* wsrc = wbf + ((uint32_t)hs << 18) + ((uint32_t)wid << 10) + ((uint32_t)lane << 3);

  f32x4 acc[4][4];
  #pragma unroll
  for (int fr = 0; fr < 4; ++fr)
    #pragma unroll
    for (int fc = 0; fc < 4; ++fc) acc[fr][fc] = (f32x4){0.f, 0.f, 0.f, 0.f};

  f32x4 rA0, rA1;

  STAGEB(0, 16384);
  FB_ALOAD(0);
  FB_PACKA(0);
  FB_ALOAD(1);
  FB_BAR2();

  #pragma unroll 1
  for (int kt = 0; kt < 30; kt += 2) {
    STAGEB(kt + 1, 32768);
    FB_COMPUTE(0, 16384);
    FB_PACKA(8192);
    FB_ALOAD(kt + 2);
    FB_BAR2();
    STAGEB(kt + 2, 16384);
    FB_COMPUTE(8192, 32768);
    FB_PACKA(0);
    FB_ALOAD(kt + 3);
    FB_BAR2();
  }
  STAGEB(31, 32768);
  FB_COMPUTE(0, 16384);
  FB_PACKA(8192);
  FB_BAR0();
  FB_COMPUTE(8192, 32768);

  float w3v[4];
  #pragma unroll
  for (int fc = 0; fc < 4; ++fc)
    w3v[fc] = W3[(hs << 7) + (((cg << 6) + (fc << 4) + l15) >> 1)];

  float* pmb = (float*)(lds);
  float* psb = pmb + 512;
  float* pnb = psb + 512;

  #pragma unroll
  for (int fr = 0; fr < 4; ++fr) {
    f32x4 mv, sv, nv;
    #pragma unroll
    for (int j = 0; j < 4; ++j) {
      float g0 = fast_tanh(acc[fr][0][j]) * w3v[0];
      float g1 = fast_tanh(acc[fr][1][j]) * w3v[1];
      float g2 = fast_tanh(acc[fr][2][j]) * w3v[2];
      float g3 = fast_tanh(acc[fr][3][j]) * w3v[3];
      float gs0 = __shfl_xor(g0, 1);
      float gs1 = __shfl_xor(g1, 1);
      float gs2 = __shfl_xor(g2, 1);
      float gs3 = __shfl_xor(g3, 1);
      float mj = fmaxf(fmaxf(acc[fr][0][j], acc[fr][1][j]),
                       fmaxf(acc[fr][2][j], acc[fr][3][j]));
      mj = fmaxf(mj, __shfl_xor(mj, 2));
      mj = fmaxf(mj, __shfl_xor(mj, 4));
      mj = fmaxf(mj, __shfl_xor(mj, 8));
      float p0 = __expf(acc[fr][0][j] - mj);
      float p1 = __expf(acc[fr][1][j] - mj);
      float p2 = __expf(acc[fr][2][j] - mj);
      float p3 = __expf(acc[fr][3][j] - mj);
      float sj = p0 + p1 + p2 + p3;
      float nj = gs0 * p0 + gs1 * p1 + gs2 * p2 + gs3 * p3;
      sj += __shfl_xor(sj, 2); nj += __shfl_xor(nj, 2);
      sj += __shfl_xor(sj, 4); nj += __shfl_xor(nj, 4);
      sj += __shfl_xor(sj, 8); nj += __shfl_xor(nj, 8);
      mv[j] = mj; sv[j] = sj; nv[j] = nj;
    }
    if (l15 == 1) {
      int idx = (cg << 7) + (rg << 6) + (fr << 4) + (lg << 2);
      *(f32x4*)&pmb[idx] = mv;
      *(f32x4*)&psb[idx] = sv;
      *(f32x4*)&pnb[idx] = nv;
    }
  }
  __syncthreads();
  if (tid < 128) {
    float m0 = pmb[tid], m1 = pmb[128 + tid], m2 = pmb[256 + tid], m3 = pmb[384 + tid];
    float M = fmaxf(fmaxf(m0, m1), fmaxf(m2, m3));
    float e0 = __expf(m0 - M), e1 = __expf(m1 - M), e2 = __expf(m2 - M), e3 = __expf(m3 - M);
    float S  = psb[tid]*e0 + psb[128+tid]*e1 + psb[256+tid]*e2 + psb[384+tid]*e3;
    float Nn = pnb[tid]*e0 + pnb[128+tid]*e1 + pnb[256+tid]*e2 + pnb[384+tid]*e3;
    size_t r = (size_t)(row0 + tid);
    pm[r * 4 + hs] = M;
    ps[r * 4 + hs] = S;
    pn[r * 4 + hs] = Nn;
  }
}

// ---------------- kernel 1b: combine h-slice partials -> a[i] --------------
__global__ void combine_a(const float* __restrict__ pm, const float* __restrict__ ps,
                          const float* __restrict__ pn, float* __restrict__ a) {
  size_t r = (size_t)blockIdx.x * 256 + threadIdx.x;
  float M = -3.4e38f;
  #pragma unroll
  for (int s = 0; s < 4; ++s) M = fmaxf(M, pm[r * 4 + s]);
  float S = 0.f, Nn = 0.f;
  #pragma unroll
  for (int s = 0; s < 4; ++s) {
    float e = __expf(pm[r * 4 + s] - M);
    S  += ps[r * 4 + s] * e;
    Nn += pn[r * 4 + s] * e;
  }
  a[r] = Nn / S;
}

// ---------------- kernel 2: segment softmax weights ----------------
static __device__ __forceinline__ int lower_bound(const int* __restrict__ batch, int key) {
  int lo = 0, hi = N_ROWS;
  while (lo < hi) { int mid = (lo + hi) >> 1; if (batch[mid] < key) lo = mid + 1; else hi = mid; }
  return lo;
}

__global__ void seg_kernel(const float* __restrict__ a, const int* __restrict__ batch,
                           float* __restrict__ w) {
  __shared__ float sm[8];
  int b = blockIdx.x;
  int start = lower_bound(batch, b);
  int end   = lower_bound(batch, b + 1);
  int tid = threadIdx.x;

  float m = -3.4e38f;
  for (int i = start + tid; i < end; i += 256) m = fmaxf(m, a[i]);
  for (int d = 1; d < 64; d <<= 1) m = fmaxf(m, __shfl_xor(m, d));
  if ((tid & 63) == 0) sm[tid >> 6] = m;
  __syncthreads();
  m = fmaxf(fmaxf(sm[0], sm[1]), fmaxf(sm[2], sm[3]));

  float s = 0.f;
  for (int i = start + tid; i < end; i += 256) s += __expf(a[i] - m);
  for (int d = 1; d < 64; d <<= 1) s += __shfl_xor(s, d);
  if ((tid & 63) == 0) sm[4 + (tid >> 6)] = s;
  __syncthreads();
  s = sm[4] + sm[5] + sm[6] + sm[7];

  float rinv = 1.0f / s;
  for (int i = start + tid; i < end; i += 256) w[i] = __expf(a[i] - m) * rinv;
}

// ---------------- kernel 3: z[b] = sum_i w_i * x_i ----------------
__global__ void z_kernel(const float* __restrict__ x, const float* __restrict__ w,
                         const int* __restrict__ batch, float* __restrict__ z) {
  int b = blockIdx.x >> 2, part = blockIdx.x & 3;
  int start = lower_bound(batch, b);
  int end   = lower_bound(batch, b + 1);
  int len = end - start;
  int ps = start + ((len * part) >> 2);
  int pe = start + ((len * (part + 1)) >> 2);
  int col = threadIdx.x << 2;

  f32x4 acc = (f32x4){0.f, 0.f, 0.f, 0.f};
  for (int i = ps; i < pe; ++i) {
    f32x4 xv = *(const f32x4*)(x + ((size_t)i << 10) + col);
    float wi = w[i];
    acc += xv * wi;
  }
  float* zp = z + ((size_t)b << 10) + col;
  atomicAdd(zp + 0, acc[0]);
  atomicAdd(zp + 1, acc[1]);
  atomicAdd(zp + 2, acc[2]);
  atomicAdd(zp + 3, acc[3]);
}

// ---------------- launch ----------------
extern "C" void kernel_launch(void* const* d_in, const int* in_sizes, int n_in,
                              void* d_out, int out_size, void* d_ws, size_t ws_size,
                              hipStream_t stream) {
  const float* x     = (const float*)d_in[0];
  const int*   batch = (const int*)d_in[1];
  const float* W1    = (const float*)d_in[2];
  const float* W2    = (const float*)d_in[3];
  const float* W3    = (const float*)d_in[4];
  float* z = (float*)d_out;

  // ws: [0,2M) wbf ; [2M,3M) a ; [3M,4M) w ; [4M,8M) pm ; [8M,12M) ps ;
  //     [12M,16M) pn ; [16M,48M) ximg (fast path only)
  unsigned short* wbf  = (unsigned short*)d_ws;
  float* a  = (float*)((char*)d_ws + (2u << 20));
  float* w  = (float*)((char*)d_ws + (3u << 20));
  float* pm = (float*)((char*)d_ws + (4u << 20));
  float* ps = (float*)((char*)d_ws + (8u << 20));
  float* pn = (float*)((char*)d_ws + (12u << 20));
  unsigned short* ximg = (unsigned short*)((char*)d_ws + (16u << 20));

  (void)hipMemsetAsync(d_out, 0, (size_t)N_SEG * D_DIM * sizeof(float), stream);

  cvt_w<<<512, 256, 0, stream>>>(W1, W2, wbf);

  if (ws_size >= ((size_t)56 << 20)) {
    (void)hipFuncSetAttribute(reinterpret_cast<const void*>(alpha_fast),
                              hipFuncAttributeMaxDynamicSharedMemorySize, 98304);
    for (int c = 0; c < 16; ++c) {
      cvt_x<<<8192, 256, 0, stream>>>(x, ximg, c);
      alpha_fast<<<256, 512, 98304, stream>>>(ximg, wbf, W3, pm, ps, pn, c);
    }
  } else {
    alpha_fb<<<8192, 512, 0, stream>>>(x, wbf, W3, pm, ps, pn);
  }

  combine_a<<<N_ROWS / 256, 256, 0, stream>>>(pm, ps, pn, a);

  seg_kernel<<<N_SEG, 256, 0, stream>>>(a, batch, w);

  z_kernel<<<N_SEG * 4, 256, 0, stream>>>(x, w, batch, z);
}